// Round 3
// baseline (396.301 us; speedup 1.0000x reference)
//
#include <hip/hip_runtime.h>
#include <hip/hip_bf16.h>

#define N_NODES 10000
#define N_EDGES 30000
#define ND 16      // node dim
#define ED 8       // edge dim
#define H 64       // hidden
#define BNECK 16   // bottleneck
#define NLAYERS 3
#define EPSN 1e-5f

#define NCHUNK 17  // 16 ew2 chunks + 1 eb2 bias chunk
#define WF_PER_LAYER (NCHUNK * 4096)   // 69632 bf16 per layer (edge W frags)
#define WFR_PER_LAYER 4096             // root W frags per layer

// k_prep fused ranges
#define R_WFG (NLAYERS * WF_PER_LAYER)            // 208896
#define R_WFR (R_WFG + NLAYERS * WFR_PER_LAYER)   // 221184
#define R_DEG (R_WFR + N_EDGES)                   // 251184
#define R_IN  (R_DEG + N_NODES * H)               // 891184

typedef __attribute__((ext_vector_type(8))) short short8;
typedef __attribute__((ext_vector_type(4))) float f32x4;

static __device__ __forceinline__ short f2bf(float f) {
    __hip_bfloat16 b = __float2bfloat16(f);
    return __builtin_bit_cast(short, b);
}

// ---- fused prep: W frags (edge + root), degree, input MLP ----
__global__ void k_prep(const float* __restrict__ x, const int* __restrict__ dst,
                       const float* __restrict__ w_in, const float* __restrict__ b_in,
                       const float* __restrict__ ew2, const float* __restrict__ eb2,
                       const float* __restrict__ wroot,
                       ushort* __restrict__ wfg, ushort* __restrict__ wfr,
                       float* __restrict__ deg, float* __restrict__ h) {
    int idx = blockIdx.x * 256 + threadIdx.x;
    if (idx < R_WFG) {
        // edge-MLP W: [l][chunk c(17)][kstep s(2)][ct(4)][lane(64)][j(8)]
        int l = idx / WF_PER_LAYER;
        int r = idx % WF_PER_LAYER;
        int c = r >> 12;
        int q = r & 4095;
        int j    = q & 7;
        int lane = (q >> 3) & 63;
        int ct   = (q >> 9) & 3;
        int s    = q >> 11;
        int k = c * 64 + s * 32 + ((lane >> 4) * 8) + j;
        int o = ct * 16 + (lane & 15);
        float v;
        if (k < 1024) v = ew2[l * 65536 + k * 64 + o];
        else          v = eb2[l * 4096 + (k - 1024) * 64 + o];
        wfg[idx] = __builtin_bit_cast(ushort, __float2bfloat16(v));
    } else if (idx < R_WFR) {
        int r2 = idx - R_WFG;
        int l = r2 / WFR_PER_LAYER;
        int q = r2 % WFR_PER_LAYER;
        int j    = q & 7;
        int lane = (q >> 3) & 63;
        int ct   = (q >> 9) & 3;
        int s    = (q >> 11) & 1;
        int k = s * 32 + ((lane >> 4) * 8) + j;
        int o = ct * 16 + (lane & 15);
        wfr[r2] = __builtin_bit_cast(ushort, __float2bfloat16(wroot[l * 4096 + k * 64 + o]));
    } else if (idx < R_DEG) {
        int e = idx - R_WFR;
        atomicAdd(&deg[dst[e]], 1.0f);
    } else if (idx < R_IN) {
        int i2 = idx - R_DEG;
        int n = i2 >> 6, o = i2 & 63;
        float s = b_in[o];
        #pragma unroll
        for (int d = 0; d < ND; ++d) s += x[n * ND + d] * w_in[d * H + o];
        h[i2] = fmaxf(s, 0.f);
    }
}

// ---- fused edge kernel (MFMA, K-split x4): msg = Z @ Wcat ----
// 938 blocks x 256 thr; block owns 32 edges; wave w owns chunks {w*4..w*4+3} (+16 for w=3).
__global__ __launch_bounds__(256) void k_msg(
    const float* __restrict__ h, const int* __restrict__ src, const int* __restrict__ dst,
    const float* __restrict__ ea, const float* __restrict__ ew1, const float* __restrict__ eb1,
    const ushort* __restrict__ wf, float* __restrict__ agg)
{
    __shared__ float h_lds[32 * 64];   // [edge][16B-swizzled cols]
    __shared__ float t_lds[32][NCHUNK];
    __shared__ float s_agg[32][68];    // padded partial-sum tile
    __shared__ int s_src[32], s_dst[32];

    const int tid = threadIdx.x;
    const int ebase = blockIdx.x * 32;

    for (int i = tid; i < 32 * 68; i += 256) ((float*)s_agg)[i] = 0.f;
    if (tid < 32) {
        int e = ebase + tid;
        bool v = e < N_EDGES;
        s_src[tid] = src[v ? e : 0];
        s_dst[tid] = v ? dst[e] : -1;
    }
    __syncthreads();

    // gather h_src rows; XOR-swizzle 16B blocks: col4' = col4 ^ (edge&15)
    #pragma unroll
    for (int p = 0; p < 2; ++p) {
        int el = p * 16 + (tid >> 4);
        int c4 = tid & 15;
        f32x4 v = *(const f32x4*)&h[s_src[el] * H + c4 * 4];
        *(f32x4*)&h_lds[el * 64 + ((c4 ^ (el & 15)) << 2)] = v;
    }
    // t = relu(ea @ ew1 + eb1): 32 edges x 16, 2 per thread
    {
        int el = tid >> 3, bg = (tid & 7) * 2;
        int eg = min(ebase + el, N_EDGES - 1);
        float av[8];
        *(f32x4*)&av[0] = *(const f32x4*)&ea[eg * ED];
        *(f32x4*)&av[4] = *(const f32x4*)&ea[eg * ED + 4];
        #pragma unroll
        for (int bb = 0; bb < 2; ++bb) {
            int b = bg + bb;
            float s = eb1[b];
            #pragma unroll
            for (int d = 0; d < ED; ++d) s += av[d] * ew1[d * BNECK + b];
            t_lds[el][b] = fmaxf(s, 0.f);
        }
    }
    if (tid < 32) t_lds[tid][16] = 1.0f;
    __syncthreads();

    const int lane = tid & 63;
    const int w = tid >> 6;
    const int l15 = lane & 15;
    const int lk2 = (lane >> 4) * 2;   // 16B-block k offset within 32-step
    const int er0 = l15;
    const int er1 = l15 + 16;

    f32x4 acc[2][4];
    #pragma unroll
    for (int i = 0; i < 2; ++i)
        #pragma unroll
        for (int j = 0; j < 4; ++j) acc[i][j] = (f32x4){0.f, 0.f, 0.f, 0.f};

#define CHUNK_BODY(cc) do { \
        const int c_ = (cc); \
        const float t0 = t_lds[er0][c_]; \
        const float t1 = t_lds[er1][c_]; \
        _Pragma("unroll") \
        for (int s = 0; s < 2; ++s) { \
            const int c40 = s * 8 + lk2; \
            short8 a0, a1; \
            { \
                const f32x4 xx = *(const f32x4*)&h_lds[er0 * 64 + ((c40 ^ l15) << 2)]; \
                const f32x4 yy = *(const f32x4*)&h_lds[er0 * 64 + (((c40 + 1) ^ l15) << 2)]; \
                a0[0] = f2bf(xx[0] * t0); a0[1] = f2bf(xx[1] * t0); \
                a0[2] = f2bf(xx[2] * t0); a0[3] = f2bf(xx[3] * t0); \
                a0[4] = f2bf(yy[0] * t0); a0[5] = f2bf(yy[1] * t0); \
                a0[6] = f2bf(yy[2] * t0); a0[7] = f2bf(yy[3] * t0); \
            } \
            { \
                const f32x4 xx = *(const f32x4*)&h_lds[er1 * 64 + ((c40 ^ l15) << 2)]; \
                const f32x4 yy = *(const f32x4*)&h_lds[er1 * 64 + (((c40 + 1) ^ l15) << 2)]; \
                a1[0] = f2bf(xx[0] * t1); a1[1] = f2bf(xx[1] * t1); \
                a1[2] = f2bf(xx[2] * t1); a1[3] = f2bf(xx[3] * t1); \
                a1[4] = f2bf(yy[0] * t1); a1[5] = f2bf(yy[1] * t1); \
                a1[6] = f2bf(yy[2] * t1); a1[7] = f2bf(yy[3] * t1); \
            } \
            const ushort* bp = wf + (size_t)(((c_ * 2 + s) * 4) * 64 + lane) * 8; \
            _Pragma("unroll") \
            for (int ct = 0; ct < 4; ++ct) { \
                short8 bfrag = *(const short8*)(bp + ct * 512); \
                acc[0][ct] = __builtin_amdgcn_mfma_f32_16x16x32_bf16(a0, bfrag, acc[0][ct], 0, 0, 0); \
                acc[1][ct] = __builtin_amdgcn_mfma_f32_16x16x32_bf16(a1, bfrag, acc[1][ct], 0, 0, 0); \
            } \
        } \
    } while (0)

    #pragma unroll
    for (int q = 0; q < 4; ++q) { CHUNK_BODY(w * 4 + q); }
    if (w == 3) { CHUNK_BODY(16); }
#undef CHUNK_BODY

    // combine K-partials in LDS (ds_add_f32)
    #pragma unroll
    for (int st = 0; st < 2; ++st) {
        #pragma unroll
        for (int r = 0; r < 4; ++r) {
            int row = st * 16 + (lane >> 4) * 4 + r;
            #pragma unroll
            for (int ct = 0; ct < 4; ++ct)
                atomicAdd(&s_agg[row][ct * 16 + l15], acc[st][ct][r]);
        }
    }
    __syncthreads();

    // one global scatter per output element
    {
        int row = tid >> 3, cb4 = (tid & 7) * 8;
        int d = s_dst[row];
        if (d >= 0) {
            #pragma unroll
            for (int j0 = 0; j0 < 8; j0 += 4) {
                f32x4 v = *(const f32x4*)&s_agg[row][cb4 + j0];
                #pragma unroll
                for (int jj = 0; jj < 4; ++jj)
                    atomicAdd(&agg[d * H + cb4 + j0 + jj], v[jj]);
            }
        }
    }
}

// ---- node kernel 1 (MFMA): out = agg/deg + h@w_root + bias; BN partial sums ----
// 625 blocks x 64 thr (1 wave, 16 nodes)
__global__ __launch_bounds__(64) void k_node1(
    const float* __restrict__ agg, const float* __restrict__ deg, const float* __restrict__ h,
    const ushort* __restrict__ wfr, const float* __restrict__ cb,
    float* __restrict__ out, float* __restrict__ sums)
{
    const int lane = threadIdx.x;
    const int l15 = lane & 15;
    const int lk8 = (lane >> 4) * 8;
    const int nb = blockIdx.x * 16;

    short8 a[2];
    #pragma unroll
    for (int s = 0; s < 2; ++s) {
        const float* hp = &h[(nb + l15) * H + s * 32 + lk8];
        f32x4 xx = *(const f32x4*)hp;
        f32x4 yy = *(const f32x4*)(hp + 4);
        a[s][0] = f2bf(xx[0]); a[s][1] = f2bf(xx[1]); a[s][2] = f2bf(xx[2]); a[s][3] = f2bf(xx[3]);
        a[s][4] = f2bf(yy[0]); a[s][5] = f2bf(yy[1]); a[s][6] = f2bf(yy[2]); a[s][7] = f2bf(yy[3]);
    }
    f32x4 acc[4] = {};
    #pragma unroll
    for (int s = 0; s < 2; ++s)
        #pragma unroll
        for (int ct = 0; ct < 4; ++ct) {
            short8 bfrag = *(const short8*)(wfr + (size_t)(((s * 4 + ct) * 64) + lane) * 8);
            acc[ct] = __builtin_amdgcn_mfma_f32_16x16x32_bf16(a[s], bfrag, acc[ct], 0, 0, 0);
        }

    float ls[4] = {}, lq[4] = {};
    #pragma unroll
    for (int r = 0; r < 4; ++r) {
        int node = nb + (lane >> 4) * 4 + r;
        float dg = deg[node];
        float inv = dg > 0.f ? 1.f / dg : 0.f;
        #pragma unroll
        for (int ct = 0; ct < 4; ++ct) {
            int c = ct * 16 + l15;
            float v = acc[ct][r] + cb[c] + inv * agg[node * H + c];
            out[node * H + c] = v;
            ls[ct] += v;
            lq[ct] += v * v;
        }
    }
    #pragma unroll
    for (int ct = 0; ct < 4; ++ct) {
        ls[ct] += __shfl_xor(ls[ct], 16, 64); ls[ct] += __shfl_xor(ls[ct], 32, 64);
        lq[ct] += __shfl_xor(lq[ct], 16, 64); lq[ct] += __shfl_xor(lq[ct], 32, 64);
    }
    if (lane < 16) {
        #pragma unroll
        for (int ct = 0; ct < 4; ++ct) {
            atomicAdd(&sums[ct * 16 + lane], ls[ct]);
            atomicAdd(&sums[64 + ct * 16 + lane], lq[ct]);
        }
    }
}

// ---- node kernel 2: BN + ReLU + residual (f32x4) ----
__global__ void k_node2(const float* __restrict__ out, const float* __restrict__ sums,
                        const float* __restrict__ gamma, const float* __restrict__ beta,
                        const float* __restrict__ hin, float* __restrict__ hout)
{
    int i4 = blockIdx.x * 256 + threadIdx.x;
    if (i4 >= N_NODES * 16) return;
    f32x4 ob = ((const f32x4*)out)[i4];
    f32x4 hb = ((const f32x4*)hin)[i4];
    int o = (i4 * 4) & 63;
    const float invN = 1.0f / (float)N_NODES;
    f32x4 res;
    #pragma unroll
    for (int j = 0; j < 4; ++j) {
        float mu = sums[o + j] * invN;
        float var = sums[64 + o + j] * invN - mu * mu;
        float scale = gamma[o + j] * rsqrtf(var + EPSN);
        float v = (ob[j] - mu) * scale + beta[o + j];
        res[j] = fmaxf(v, 0.f) + hb[j];
    }
    ((f32x4*)hout)[i4] = res;
}

extern "C" void kernel_launch(void* const* d_in, const int* in_sizes, int n_in,
                              void* d_out, int out_size, void* d_ws, size_t ws_size,
                              hipStream_t stream) {
    const float* x     = (const float*)d_in[0];
    const int*   ei    = (const int*)  d_in[1];
    const float* ea    = (const float*)d_in[2];
    const float* w_in  = (const float*)d_in[3];
    const float* b_in  = (const float*)d_in[4];
    const float* ew1   = (const float*)d_in[5];   // [3,8,16]
    const float* eb1   = (const float*)d_in[6];   // [3,16]
    const float* ew2   = (const float*)d_in[7];   // [3,16,4096]
    const float* eb2   = (const float*)d_in[8];   // [3,4096]
    const float* wroot = (const float*)d_in[9];   // [3,64,64]
    const float* cb    = (const float*)d_in[10];  // [3,64]
    const float* gamma = (const float*)d_in[11];  // [3,64]
    const float* beta  = (const float*)d_in[12];  // [3,64]
    float* outp = (float*)d_out;

    float* ws   = (float*)d_ws;
    float* deg  = ws;                              // 10000
    float* agg  = deg + N_NODES;                   // 3 * 640000
    float* sums = agg + 3 * N_NODES * H;           // 3 * 128
    float* h    = sums + 3 * 128;                  // 640000
    float* outb = h + N_NODES * H;                 // 640000
    ushort* wfg = (ushort*)(outb + N_NODES * H);   // 3*69632 bf16
    ushort* wfr = wfg + NLAYERS * WF_PER_LAYER;    // 3*4096 bf16

    const int* srcp = ei;
    const int* dstp = ei + N_EDGES;

    // zero deg + 3*agg + 3*sums in one shot
    hipMemsetAsync(ws, 0, (size_t)(N_NODES + 3 * N_NODES * H + 3 * 128) * sizeof(float), stream);
    k_prep<<<(R_IN + 255) / 256, 256, 0, stream>>>(x, dstp, w_in, b_in, ew2, eb2, wroot,
                                                   wfg, wfr, deg, h);

    for (int l = 0; l < NLAYERS; ++l) {
        float* agg_l  = agg + (size_t)l * N_NODES * H;
        float* sums_l = sums + l * 128;
        k_msg<<<(N_EDGES + 31) / 32, 256, 0, stream>>>(
            h, srcp, dstp, ea,
            ew1 + l * ED * BNECK, eb1 + l * BNECK,
            wfg + (size_t)l * WF_PER_LAYER, agg_l);
        k_node1<<<N_NODES / 16, 64, 0, stream>>>(
            agg_l, deg, h, wfr + (size_t)l * WFR_PER_LAYER, cb + l * H, outb, sums_l);
        float* hout = (l == NLAYERS - 1) ? outp : h;
        k_node2<<<(N_NODES * 16 + 255) / 256, 256, 0, stream>>>(
            outb, sums_l, gamma + l * H, beta + l * H, h, hout);
    }
}

// Round 5
// 306.074 us; speedup vs baseline: 1.2948x; 1.2948x over previous
//
#include <hip/hip_runtime.h>
#include <hip/hip_bf16.h>

#define N_NODES 10000
#define N_EDGES 30000
#define ND 16      // node dim
#define ED 8       // edge dim
#define H 64       // hidden
#define BNECK 16   // bottleneck
#define NLAYERS 3
#define EPSN 1e-5f

#define NCHUNK 17  // 16 ew2 chunks + 1 eb2 bias chunk
#define WF_PER_LAYER (NCHUNK * 4096)   // 69632 bf16 per layer (edge W frags)
#define WFR_PER_LAYER 4096             // root W frags per layer

// k_prep fused ranges
#define R_WFG (NLAYERS * WF_PER_LAYER)            // 208896
#define R_WFR (R_WFG + NLAYERS * WFR_PER_LAYER)   // 221184
#define R_DEG (R_WFR + N_EDGES)                   // 251184
#define R_IN  (R_DEG + N_NODES * H)               // 891184

typedef __attribute__((ext_vector_type(8))) short short8;
typedef __attribute__((ext_vector_type(4))) float f32x4;

static __device__ __forceinline__ short f2bf(float f) {
    __hip_bfloat16 b = __float2bfloat16(f);
    return __builtin_bit_cast(short, b);
}

// ---- fused prep: W frags (edge + root), degree, input MLP ----
__global__ void k_prep(const float* __restrict__ x, const int* __restrict__ dst,
                       const float* __restrict__ w_in, const float* __restrict__ b_in,
                       const float* __restrict__ ew2, const float* __restrict__ eb2,
                       const float* __restrict__ wroot,
                       ushort* __restrict__ wfg, ushort* __restrict__ wfr,
                       float* __restrict__ deg, float* __restrict__ h) {
    int idx = blockIdx.x * 256 + threadIdx.x;
    if (idx < R_WFG) {
        // edge-MLP W: [l][chunk c(17)][kstep s(2)][ct(4)][lane(64)][j(8)]
        int l = idx / WF_PER_LAYER;
        int r = idx % WF_PER_LAYER;
        int c = r >> 12;
        int q = r & 4095;
        int j    = q & 7;
        int lane = (q >> 3) & 63;
        int ct   = (q >> 9) & 3;
        int s    = q >> 11;
        int k = c * 64 + s * 32 + ((lane >> 4) * 8) + j;
        int o = ct * 16 + (lane & 15);
        float v;
        if (k < 1024) v = ew2[l * 65536 + k * 64 + o];
        else          v = eb2[l * 4096 + (k - 1024) * 64 + o];
        wfg[idx] = __builtin_bit_cast(ushort, __float2bfloat16(v));
    } else if (idx < R_WFR) {
        int r2 = idx - R_WFG;
        int l = r2 / WFR_PER_LAYER;
        int q = r2 % WFR_PER_LAYER;
        int j    = q & 7;
        int lane = (q >> 3) & 63;
        int ct   = (q >> 9) & 3;
        int s    = (q >> 11) & 1;
        int k = s * 32 + ((lane >> 4) * 8) + j;
        int o = ct * 16 + (lane & 15);
        wfr[r2] = __builtin_bit_cast(ushort, __float2bfloat16(wroot[l * 4096 + k * 64 + o]));
    } else if (idx < R_DEG) {
        int e = idx - R_WFR;
        atomicAdd(&deg[dst[e]], 1.0f);
    } else if (idx < R_IN) {
        int i2 = idx - R_DEG;
        int n = i2 >> 6, o = i2 & 63;
        float s = b_in[o];
        #pragma unroll
        for (int d = 0; d < ND; ++d) s += x[n * ND + d] * w_in[d * H + o];
        h[i2] = fmaxf(s, 0.f);
    }
}

// ---- fused edge kernel (MFMA, K-split x4): msg = Z @ Wcat ----
// 938 blocks x 256 thr; block owns 32 edges; wave w owns chunks {w*4..w*4+3} (+16 for w=3).
__global__ __launch_bounds__(256) void k_msg(
    const float* __restrict__ h, const int* __restrict__ src, const int* __restrict__ dst,
    const float* __restrict__ ea, const float* __restrict__ ew1, const float* __restrict__ eb1,
    const ushort* __restrict__ wf, float* __restrict__ agg)
{
    __shared__ float h_lds[32 * 64];   // [edge][16B-swizzled cols]
    __shared__ float t_lds[32][NCHUNK];
    __shared__ float s_agg[32][68];    // padded partial-sum tile
    __shared__ int s_src[32], s_dst[32];

    const int tid = threadIdx.x;
    const int ebase = blockIdx.x * 32;

    for (int i = tid; i < 32 * 68; i += 256) ((float*)s_agg)[i] = 0.f;
    if (tid < 32) {
        int e = ebase + tid;
        bool v = e < N_EDGES;
        s_src[tid] = src[v ? e : 0];
        s_dst[tid] = v ? dst[e] : -1;
    }
    __syncthreads();

    // gather h_src rows; XOR-swizzle 16B blocks: col4' = col4 ^ (edge&15)
    #pragma unroll
    for (int p = 0; p < 2; ++p) {
        int el = p * 16 + (tid >> 4);
        int c4 = tid & 15;
        f32x4 v = *(const f32x4*)&h[s_src[el] * H + c4 * 4];
        *(f32x4*)&h_lds[el * 64 + ((c4 ^ (el & 15)) << 2)] = v;
    }
    // t = relu(ea @ ew1 + eb1): 32 edges x 16, 2 per thread
    {
        int el = tid >> 3, bg = (tid & 7) * 2;
        int eg = min(ebase + el, N_EDGES - 1);
        float av[8];
        *(f32x4*)&av[0] = *(const f32x4*)&ea[eg * ED];
        *(f32x4*)&av[4] = *(const f32x4*)&ea[eg * ED + 4];
        #pragma unroll
        for (int bb = 0; bb < 2; ++bb) {
            int b = bg + bb;
            float s = eb1[b];
            #pragma unroll
            for (int d = 0; d < ED; ++d) s += av[d] * ew1[d * BNECK + b];
            t_lds[el][b] = fmaxf(s, 0.f);
        }
    }
    if (tid < 32) t_lds[tid][16] = 1.0f;
    __syncthreads();

    const int lane = tid & 63;
    const int w = tid >> 6;
    const int l15 = lane & 15;
    const int lk2 = (lane >> 4) * 2;   // 16B-block k offset within 32-step
    const int er0 = l15;
    const int er1 = l15 + 16;

    f32x4 acc[2][4];
    #pragma unroll
    for (int i = 0; i < 2; ++i)
        #pragma unroll
        for (int j = 0; j < 4; ++j) acc[i][j] = (f32x4){0.f, 0.f, 0.f, 0.f};

#define CHUNK_BODY(cc) do { \
        const int c_ = (cc); \
        const float t0 = t_lds[er0][c_]; \
        const float t1 = t_lds[er1][c_]; \
        _Pragma("unroll") \
        for (int s = 0; s < 2; ++s) { \
            const int c40 = s * 8 + lk2; \
            short8 a0, a1; \
            { \
                const f32x4 xx = *(const f32x4*)&h_lds[er0 * 64 + ((c40 ^ l15) << 2)]; \
                const f32x4 yy = *(const f32x4*)&h_lds[er0 * 64 + (((c40 + 1) ^ l15) << 2)]; \
                a0[0] = f2bf(xx[0] * t0); a0[1] = f2bf(xx[1] * t0); \
                a0[2] = f2bf(xx[2] * t0); a0[3] = f2bf(xx[3] * t0); \
                a0[4] = f2bf(yy[0] * t0); a0[5] = f2bf(yy[1] * t0); \
                a0[6] = f2bf(yy[2] * t0); a0[7] = f2bf(yy[3] * t0); \
            } \
            { \
                const f32x4 xx = *(const f32x4*)&h_lds[er1 * 64 + ((c40 ^ l15) << 2)]; \
                const f32x4 yy = *(const f32x4*)&h_lds[er1 * 64 + (((c40 + 1) ^ l15) << 2)]; \
                a1[0] = f2bf(xx[0] * t1); a1[1] = f2bf(xx[1] * t1); \
                a1[2] = f2bf(xx[2] * t1); a1[3] = f2bf(xx[3] * t1); \
                a1[4] = f2bf(yy[0] * t1); a1[5] = f2bf(yy[1] * t1); \
                a1[6] = f2bf(yy[2] * t1); a1[7] = f2bf(yy[3] * t1); \
            } \
            const ushort* bp = wf + (size_t)(((c_ * 2 + s) * 4) * 64 + lane) * 8; \
            _Pragma("unroll") \
            for (int ct = 0; ct < 4; ++ct) { \
                short8 bfrag = *(const short8*)(bp + ct * 512); \
                acc[0][ct] = __builtin_amdgcn_mfma_f32_16x16x32_bf16(a0, bfrag, acc[0][ct], 0, 0, 0); \
                acc[1][ct] = __builtin_amdgcn_mfma_f32_16x16x32_bf16(a1, bfrag, acc[1][ct], 0, 0, 0); \
            } \
        } \
    } while (0)

    #pragma unroll
    for (int q = 0; q < 4; ++q) { CHUNK_BODY(w * 4 + q); }
    if (w == 3) { CHUNK_BODY(16); }
#undef CHUNK_BODY

    // combine K-partials in LDS (ds_add_f32)
    #pragma unroll
    for (int st = 0; st < 2; ++st) {
        #pragma unroll
        for (int r = 0; r < 4; ++r) {
            int row = st * 16 + (lane >> 4) * 4 + r;
            #pragma unroll
            for (int ct = 0; ct < 4; ++ct)
                atomicAdd(&s_agg[row][ct * 16 + l15], acc[st][ct][r]);
        }
    }
    __syncthreads();

    // coalesced scatter: 64 lanes = 1 row x 64 consecutive cols (write-minimal)
    #pragma unroll
    for (int rep = 0; rep < 8; ++rep) {
        int i2 = rep * 256 + tid;
        int row = i2 >> 6, col = i2 & 63;
        int d = s_dst[row];
        if (d >= 0) atomicAdd(&agg[d * H + col], s_agg[row][col]);
    }
}

// ---- node kernel 1 (MFMA): out = agg/deg + h@w_root + bias; BN partial sums ----
// 625 blocks x 64 thr (1 wave, 16 nodes)
__global__ __launch_bounds__(64) void k_node1(
    const float* __restrict__ agg, const float* __restrict__ deg, const float* __restrict__ h,
    const ushort* __restrict__ wfr, const float* __restrict__ cb,
    float* __restrict__ out, float* __restrict__ sums)
{
    const int lane = threadIdx.x;
    const int l15 = lane & 15;
    const int lk8 = (lane >> 4) * 8;
    const int nb = blockIdx.x * 16;

    short8 a[2];
    #pragma unroll
    for (int s = 0; s < 2; ++s) {
        const float* hp = &h[(nb + l15) * H + s * 32 + lk8];
        f32x4 xx = *(const f32x4*)hp;
        f32x4 yy = *(const f32x4*)(hp + 4);
        a[s][0] = f2bf(xx[0]); a[s][1] = f2bf(xx[1]); a[s][2] = f2bf(xx[2]); a[s][3] = f2bf(xx[3]);
        a[s][4] = f2bf(yy[0]); a[s][5] = f2bf(yy[1]); a[s][6] = f2bf(yy[2]); a[s][7] = f2bf(yy[3]);
    }
    f32x4 acc[4] = {};
    #pragma unroll
    for (int s = 0; s < 2; ++s)
        #pragma unroll
        for (int ct = 0; ct < 4; ++ct) {
            short8 bfrag = *(const short8*)(wfr + (size_t)(((s * 4 + ct) * 64) + lane) * 8);
            acc[ct] = __builtin_amdgcn_mfma_f32_16x16x32_bf16(a[s], bfrag, acc[ct], 0, 0, 0);
        }

    float ls[4] = {}, lq[4] = {};
    #pragma unroll
    for (int r = 0; r < 4; ++r) {
        int node = nb + (lane >> 4) * 4 + r;
        float dg = deg[node];
        float inv = dg > 0.f ? 1.f / dg : 0.f;
        #pragma unroll
        for (int ct = 0; ct < 4; ++ct) {
            int c = ct * 16 + l15;
            float v = acc[ct][r] + cb[c] + inv * agg[node * H + c];
            out[node * H + c] = v;
            ls[ct] += v;
            lq[ct] += v * v;
        }
    }
    #pragma unroll
    for (int ct = 0; ct < 4; ++ct) {
        ls[ct] += __shfl_xor(ls[ct], 16, 64); ls[ct] += __shfl_xor(ls[ct], 32, 64);
        lq[ct] += __shfl_xor(lq[ct], 16, 64); lq[ct] += __shfl_xor(lq[ct], 32, 64);
    }
    if (lane < 16) {
        #pragma unroll
        for (int ct = 0; ct < 4; ++ct) {
            atomicAdd(&sums[ct * 16 + lane], ls[ct]);
            atomicAdd(&sums[64 + ct * 16 + lane], lq[ct]);
        }
    }
}

// ---- node kernel 2: BN + ReLU + residual (f32x4) ----
__global__ void k_node2(const float* __restrict__ out, const float* __restrict__ sums,
                        const float* __restrict__ gamma, const float* __restrict__ beta,
                        const float* __restrict__ hin, float* __restrict__ hout)
{
    int i4 = blockIdx.x * 256 + threadIdx.x;
    if (i4 >= N_NODES * 16) return;
    f32x4 ob = ((const f32x4*)out)[i4];
    f32x4 hb = ((const f32x4*)hin)[i4];
    int o = (i4 * 4) & 63;
    const float invN = 1.0f / (float)N_NODES;
    f32x4 res;
    #pragma unroll
    for (int j = 0; j < 4; ++j) {
        float mu = sums[o + j] * invN;
        float var = sums[64 + o + j] * invN - mu * mu;
        float scale = gamma[o + j] * rsqrtf(var + EPSN);
        float v = (ob[j] - mu) * scale + beta[o + j];
        res[j] = fmaxf(v, 0.f) + hb[j];
    }
    ((f32x4*)hout)[i4] = res;
}

extern "C" void kernel_launch(void* const* d_in, const int* in_sizes, int n_in,
                              void* d_out, int out_size, void* d_ws, size_t ws_size,
                              hipStream_t stream) {
    const float* x     = (const float*)d_in[0];
    const int*   ei    = (const int*)  d_in[1];
    const float* ea    = (const float*)d_in[2];
    const float* w_in  = (const float*)d_in[3];
    const float* b_in  = (const float*)d_in[4];
    const float* ew1   = (const float*)d_in[5];   // [3,8,16]
    const float* eb1   = (const float*)d_in[6];   // [3,16]
    const float* ew2   = (const float*)d_in[7];   // [3,16,4096]
    const float* eb2   = (const float*)d_in[8];   // [3,4096]
    const float* wroot = (const float*)d_in[9];   // [3,64,64]
    const float* cb    = (const float*)d_in[10];  // [3,64]
    const float* gamma = (const float*)d_in[11];  // [3,64]
    const float* beta  = (const float*)d_in[12];  // [3,64]
    float* outp = (float*)d_out;

    float* ws   = (float*)d_ws;
    float* deg  = ws;                              // 10000
    float* agg  = deg + N_NODES;                   // 3 * 640000
    float* sums = agg + 3 * N_NODES * H;           // 3 * 128
    float* h    = sums + 3 * 128;                  // 640000
    float* outb = h + N_NODES * H;                 // 640000
    ushort* wfg = (ushort*)(outb + N_NODES * H);   // 3*69632 bf16
    ushort* wfr = wfg + NLAYERS * WF_PER_LAYER;    // 3*4096 bf16

    const int* srcp = ei;
    const int* dstp = ei + N_EDGES;

    // zero deg + 3*agg + 3*sums in one shot
    hipMemsetAsync(ws, 0, (size_t)(N_NODES + 3 * N_NODES * H + 3 * 128) * sizeof(float), stream);
    k_prep<<<(R_IN + 255) / 256, 256, 0, stream>>>(x, dstp, w_in, b_in, ew2, eb2, wroot,
                                                   wfg, wfr, deg, h);

    for (int l = 0; l < NLAYERS; ++l) {
        float* agg_l  = agg + (size_t)l * N_NODES * H;
        float* sums_l = sums + l * 128;
        k_msg<<<(N_EDGES + 31) / 32, 256, 0, stream>>>(
            h, srcp, dstp, ea,
            ew1 + l * ED * BNECK, eb1 + l * BNECK,
            wfg + (size_t)l * WF_PER_LAYER, agg_l);
        k_node1<<<N_NODES / 16, 64, 0, stream>>>(
            agg_l, deg, h, wfr + (size_t)l * WFR_PER_LAYER, cb + l * H, outb, sums_l);
        float* hout = (l == NLAYERS - 1) ? outp : h;
        k_node2<<<(N_NODES * 16 + 255) / 256, 256, 0, stream>>>(
            outb, sums_l, gamma + l * H, beta + l * H, h, hout);
    }
}